// Round 4
// baseline (129.479 us; speedup 1.0000x reference)
//
#include <hip/hip_runtime.h>
#include <hip/hip_bf16.h>

// Problem constants
#define NB    4096          // batch
#define ND    256           // dim
#define NP    2             // positives per anchor
#define TOT   (NB * 3)      // 12288 rows: [a | p0 | p1]
#define NCHUNK 24           // 3 parts x 8 chunks; each chunk within one part
#define COLS_PER_CHUNK (TOT / NCHUNK)          // 512
#define TILES (COLS_PER_CHUNK / 16)            // 32
#define PITCH 528                               // 512B row + 16B pad
#define NEG_INIT (-4.0f)

typedef __bf16 bf16x8 __attribute__((ext_vector_type(8)));
typedef float  f32x4  __attribute__((ext_vector_type(4)));

// ws layout (bytes)
#define WS_F_OFF    0                            // ushort[12288*256] bf16 normalized
#define WS_POS_OFF  (TOT * ND * 2)               // float[4096*2] pos distances
#define WS_PART_OFF (WS_POS_OFF + NB * NP * 4)   // float[3][4096][8] partial maxima

__device__ __forceinline__ unsigned short f2bf(float f) {
    unsigned u = __float_as_uint(f);
    u += 0x7fffu + ((u >> 16) & 1u);   // round-to-nearest-even
    return (unsigned short)(u >> 16);
}

// Kernel 1: normalize rows of [a | p0 | p1] -> bf16 matrix F; p-rows also emit
// the exact fp32 positive distance. One wave per row.
__global__ void norm_pos_kernel(const float* __restrict__ anchor,
                                const float* __restrict__ positive,
                                unsigned short* __restrict__ F,
                                float* __restrict__ posArr) {
    int wid = threadIdx.x >> 6, lane = threadIdx.x & 63;
    int row = blockIdx.x * 4 + wid;              // grid = 3072
    if (row < NB) {
        const float* src = anchor + (size_t)row * ND;
        float4 x = *(const float4*)(src + lane * 4);
        float ss = x.x * x.x + x.y * x.y + x.z * x.z + x.w * x.w;
        #pragma unroll
        for (int m = 1; m < 64; m <<= 1) ss += __shfl_xor(ss, m, 64);
        float inv = 1.0f / fmaxf(sqrtf(ss), 1e-12f);
        ushort4 o;
        o.x = f2bf(x.x * inv); o.y = f2bf(x.y * inv);
        o.z = f2bf(x.z * inv); o.w = f2bf(x.w * inv);
        *(ushort4*)(F + (size_t)row * ND + lane * 4) = o;
    } else {
        int q = row - NB;
        int v = q >> 12;                         // 0 or 1
        int j = q & (NB - 1);
        const float* sp = positive + (size_t)(j * NP + v) * ND;
        const float* sa = anchor + (size_t)j * ND;
        float4 xp = *(const float4*)(sp + lane * 4);
        float4 xa = *(const float4*)(sa + lane * 4);
        float sspv = xp.x * xp.x + xp.y * xp.y + xp.z * xp.z + xp.w * xp.w;
        float ssa  = xa.x * xa.x + xa.y * xa.y + xa.z * xa.z + xa.w * xa.w;
        float dot  = xa.x * xp.x + xa.y * xp.y + xa.z * xp.z + xa.w * xp.w;
        #pragma unroll
        for (int m = 1; m < 64; m <<= 1) {
            sspv += __shfl_xor(sspv, m, 64);
            ssa  += __shfl_xor(ssa, m, 64);
            dot  += __shfl_xor(dot, m, 64);
        }
        float invp = 1.0f / fmaxf(sqrtf(sspv), 1e-12f);
        ushort4 o;
        o.x = f2bf(xp.x * invp); o.y = f2bf(xp.y * invp);
        o.z = f2bf(xp.z * invp); o.w = f2bf(xp.w * invp);
        *(ushort4*)(F + (size_t)row * ND + lane * 4) = o;
        if (lane == 0) {
            float inva = 1.0f / fmaxf(sqrtf(ssa), 1e-12f);
            float dn = dot * inva * invp;
            float sq = 2.0f - 2.0f * dn;
            posArr[j * NP + v] = sqrtf(fmaxf(sq, 1e-12f));
        }
    }
}

// Kernel 2: fused masked-max Gram. Block = 2 waves x 64 rows = 256 rows;
// LDS-staged double-buffered 16-col B tiles shared by both waves.
// 64 rows/wave halves LDS B-read traffic per unit work vs 32 rows/wave.
__global__ __launch_bounds__(128) void gram_max_kernel(
        const unsigned short* __restrict__ F,
        const int* __restrict__ labels,
        float* __restrict__ partials) {
    __shared__ unsigned char lds[2][16 * PITCH];
    __shared__ int slab[COLS_PER_CHUNK];         // column labels for this chunk
    int tid = threadIdx.x;
    int wid = tid >> 6, lane = tid & 63;
    int l15 = lane & 15, quad = lane >> 4;
    int rowBase = blockIdx.x * 128 + wid * 64;   // gridDim.x = 32
    int chunk = blockIdx.y;                      // gridDim.y = NCHUNK
    int col0 = chunk * COLS_PER_CHUNK;
    int part = col0 >> 12;                       // block-uniform: 0=aa, 1=p0, 2=p1
    const unsigned char* Fb = (const unsigned char*)F;

    // Stage this chunk's 512 column labels into LDS (labels repeat mod NB).
    ((int4*)slab)[tid] = ((const int4*)(labels + (col0 & (NB - 1))))[tid];

    // Staging map: 8 threads per column, 4x16B segments per thread.
    int scol = tid >> 3, sseg = tid & 7;

    // Preload A fragments: af[s][kk] covers rows rowBase+s*16.., K = kk*32.
    bf16x8 af[4][8];
    #pragma unroll
    for (int s = 0; s < 4; ++s) {
        const unsigned char* ar = Fb + (size_t)(rowBase + s * 16 + l15) * 512 + quad * 16;
        #pragma unroll
        for (int kk = 0; kk < 8; ++kk)
            af[s][kk] = *(const bf16x8*)(ar + kk * 64);
    }
    // Row labels, byte-packed (labels < 200 fit a byte): rlp[s] holds the 4
    // C rows (quad*4+r) of set s. Saves 12 VGPRs vs unpacked.
    unsigned rlp[4];
    #pragma unroll
    for (int s = 0; s < 4; ++s) {
        const int* lb = labels + rowBase + s * 16 + quad * 4;
        rlp[s] = (unsigned)lb[0] | ((unsigned)lb[1] << 8)
               | ((unsigned)lb[2] << 16) | ((unsigned)lb[3] << 24);
    }

    float vmax[4][4];
    #pragma unroll
    for (int s = 0; s < 4; ++s)
        #pragma unroll
        for (int r = 0; r < 4; ++r) vmax[s][r] = NEG_INIT;

    float4 rg[4];  // prefetch registers (one 16-col tile / block)
    auto gload = [&](int ct) {
        const unsigned char* g = Fb + (size_t)(col0 + ct * 16 + scol) * 512 + sseg * 64;
        #pragma unroll
        for (int j = 0; j < 4; ++j) rg[j] = *(const float4*)(g + j * 16);
    };
    auto swrite = [&](int buf) {
        unsigned char* p = &lds[buf][scol * PITCH + sseg * 64];
        #pragma unroll
        for (int j = 0; j < 4; ++j) *(float4*)(p + j * 16) = rg[j];
    };

    gload(0); swrite(0);
    gload(1);
    __syncthreads();

    for (int ct = 0; ct < TILES; ++ct) {
        int buf = ct & 1;
        bf16x8 bfr[8];
        #pragma unroll
        for (int kk = 0; kk < 8; ++kk)
            bfr[kk] = *(const bf16x8*)&lds[buf][l15 * PITCH + quad * 16 + kk * 64];

        if (ct + 1 < TILES) swrite(buf ^ 1);   // stage next tile (regs already loaded)
        if (ct + 2 < TILES) gload(ct + 2);     // prefetch tile after next

        int lc = slab[ct * 16 + l15];          // column label (broadcast within quad)
        unsigned lcq = (unsigned)lc * 0x01010101u;

        // 4 independent MFMA chains (one per 16-row set), depth 8
        f32x4 acc[4];
        #pragma unroll
        for (int s = 0; s < 4; ++s) acc[s] = (f32x4){0.f, 0.f, 0.f, 0.f};
        #pragma unroll
        for (int kk = 0; kk < 8; ++kk)
            #pragma unroll
            for (int s = 0; s < 4; ++s)
                acc[s] = __builtin_amdgcn_mfma_f32_16x16x32_bf16(af[s][kk], bfr[kk], acc[s], 0, 0, 0);

        #pragma unroll
        for (int s = 0; s < 4; ++s) {
            unsigned x = rlp[s] ^ lcq;         // byte r == 0 iff labels equal
            #pragma unroll
            for (int r = 0; r < 4; ++r) {
                bool neq = ((x >> (8 * r)) & 0xffu) != 0u;
                vmax[s][r] = fmaxf(vmax[s][r], neq ? acc[s][r] : NEG_INIT);
            }
        }
        __syncthreads();
    }

    // Reduce max across the 16 column-lanes (same quad = same rows)
    #pragma unroll
    for (int m = 1; m < 16; m <<= 1)
        #pragma unroll
        for (int s = 0; s < 4; ++s)
            #pragma unroll
            for (int r = 0; r < 4; ++r)
                vmax[s][r] = fmaxf(vmax[s][r], __shfl_xor(vmax[s][r], m, 64));

    if (l15 == 0) {
        #pragma unroll
        for (int s = 0; s < 4; ++s)
            #pragma unroll
            for (int r = 0; r < 4; ++r) {
                int row = rowBase + s * 16 + quad * 4 + r;
                partials[(size_t)part * NB * 8 + (size_t)row * 8 + (chunk & 7)] = vmax[s][r];
            }
    }
}

// Kernel 3: combine per-part chunk partials -> neg distances -> hinge -> mean.
__global__ void finalize_kernel(const float* __restrict__ partials,
                                const float* __restrict__ posArr,
                                float* __restrict__ out) {
    int row = blockIdx.x * 256 + threadIdx.x;    // grid = 16 -> 4096 rows
    const float* pa = partials + (size_t)row * 8;
    const float* pb = pa + (size_t)NB * 8;
    const float* pc = pb + (size_t)NB * 8;
    float ma = NEG_INIT, m0 = NEG_INIT, m1 = NEG_INIT;
    #pragma unroll
    for (int j = 0; j < 8; ++j) {
        ma = fmaxf(ma, pa[j]);
        m0 = fmaxf(m0, pb[j]);
        m1 = fmaxf(m1, pc[j]);
    }
    float n0 = sqrtf(fmaxf(2.0f - 2.0f * fmaxf(ma, m0), 1e-12f));
    float n1 = sqrtf(fmaxf(2.0f - 2.0f * fmaxf(ma, m1), 1e-12f));
    float l = fmaxf(posArr[row * 2 + 0] - n0 + 1.0f, 0.0f)
            + fmaxf(posArr[row * 2 + 1] - n1 + 1.0f, 0.0f);
    int lane = threadIdx.x & 63, wid = threadIdx.x >> 6;
    #pragma unroll
    for (int m = 1; m < 64; m <<= 1) l += __shfl_xor(l, m, 64);
    __shared__ float wsum[4];
    if (lane == 0) wsum[wid] = l;
    __syncthreads();
    if (threadIdx.x == 0) {
        float s = wsum[0] + wsum[1] + wsum[2] + wsum[3];
        atomicAdd(out, s * (1.0f / (NB * NP)));
    }
}

extern "C" void kernel_launch(void* const* d_in, const int* in_sizes, int n_in,
                              void* d_out, int out_size, void* d_ws, size_t ws_size,
                              hipStream_t stream) {
    const float* anchor   = (const float*)d_in[0];
    const float* positive = (const float*)d_in[1];
    const int*   labels   = (const int*)d_in[2];
    float* out = (float*)d_out;

    unsigned short* F = (unsigned short*)((char*)d_ws + WS_F_OFF);
    float* posArr     = (float*)((char*)d_ws + WS_POS_OFF);
    float* partials   = (float*)((char*)d_ws + WS_PART_OFF);

    norm_pos_kernel<<<TOT / 4, 256, 0, stream>>>(anchor, positive, F, posArr);
    gram_max_kernel<<<dim3(NB / 128, NCHUNK), 128, 0, stream>>>(F, labels, partials);
    hipMemsetAsync(d_out, 0, sizeof(float), stream);
    finalize_kernel<<<NB / 256, 256, 0, stream>>>(partials, posArr, out);
}

// Round 5
// 105.654 us; speedup vs baseline: 1.2255x; 1.2255x over previous
//
#include <hip/hip_runtime.h>
#include <hip/hip_bf16.h>

// Problem constants
#define NB    4096          // batch
#define ND    256           // dim
#define NP    2             // positives per anchor
#define TOT   (NB * 3)      // 12288 rows: [a | p0 | p1]
#define NCHUNK 48           // 3 parts x 16 chunks; each chunk within one part
#define COLS_PER_CHUNK (TOT / NCHUNK)          // 256
#define TILES (COLS_PER_CHUNK / 16)            // 16
#define PITCH 528                               // 512B row + 16B pad (conflict-free)
#define NEG_INIT (-4.0f)

typedef __bf16 bf16x8 __attribute__((ext_vector_type(8)));
typedef float  f32x4  __attribute__((ext_vector_type(4)));

// ws layout (bytes)
#define WS_F_OFF    0                            // ushort[12288*256] bf16 normalized
#define WS_POS_OFF  (TOT * ND * 2)               // float[4096*2] pos distances
#define WS_PART_OFF (WS_POS_OFF + NB * NP * 4)   // float[3][4096][16] partial maxima

__device__ __forceinline__ unsigned short f2bf(float f) {
    unsigned u = __float_as_uint(f);
    u += 0x7fffu + ((u >> 16) & 1u);   // round-to-nearest-even
    return (unsigned short)(u >> 16);
}

// Kernel 1: normalize rows of [a | p0 | p1] -> bf16 matrix F; p-rows also emit
// the exact fp32 positive distance. One wave per row.
__global__ void norm_pos_kernel(const float* __restrict__ anchor,
                                const float* __restrict__ positive,
                                unsigned short* __restrict__ F,
                                float* __restrict__ posArr) {
    int wid = threadIdx.x >> 6, lane = threadIdx.x & 63;
    int row = blockIdx.x * 4 + wid;              // grid = 3072
    if (row < NB) {
        const float* src = anchor + (size_t)row * ND;
        float4 x = *(const float4*)(src + lane * 4);
        float ss = x.x * x.x + x.y * x.y + x.z * x.z + x.w * x.w;
        #pragma unroll
        for (int m = 1; m < 64; m <<= 1) ss += __shfl_xor(ss, m, 64);
        float inv = 1.0f / fmaxf(sqrtf(ss), 1e-12f);
        ushort4 o;
        o.x = f2bf(x.x * inv); o.y = f2bf(x.y * inv);
        o.z = f2bf(x.z * inv); o.w = f2bf(x.w * inv);
        *(ushort4*)(F + (size_t)row * ND + lane * 4) = o;
    } else {
        int q = row - NB;
        int v = q >> 12;                         // 0 or 1
        int j = q & (NB - 1);
        const float* sp = positive + (size_t)(j * NP + v) * ND;
        const float* sa = anchor + (size_t)j * ND;
        float4 xp = *(const float4*)(sp + lane * 4);
        float4 xa = *(const float4*)(sa + lane * 4);
        float sspv = xp.x * xp.x + xp.y * xp.y + xp.z * xp.z + xp.w * xp.w;
        float ssa  = xa.x * xa.x + xa.y * xa.y + xa.z * xa.z + xa.w * xa.w;
        float dot  = xa.x * xp.x + xa.y * xp.y + xa.z * xp.z + xa.w * xp.w;
        #pragma unroll
        for (int m = 1; m < 64; m <<= 1) {
            sspv += __shfl_xor(sspv, m, 64);
            ssa  += __shfl_xor(ssa, m, 64);
            dot  += __shfl_xor(dot, m, 64);
        }
        float invp = 1.0f / fmaxf(sqrtf(sspv), 1e-12f);
        ushort4 o;
        o.x = f2bf(xp.x * invp); o.y = f2bf(xp.y * invp);
        o.z = f2bf(xp.z * invp); o.w = f2bf(xp.w * invp);
        *(ushort4*)(F + (size_t)row * ND + lane * 4) = o;
        if (lane == 0) {
            float inva = 1.0f / fmaxf(sqrtf(ssa), 1e-12f);
            float dn = dot * inva * invp;
            float sq = 2.0f - 2.0f * dn;
            posArr[j * NP + v] = sqrtf(fmaxf(sq, 1e-12f));
        }
    }
}

// Kernel 2: fused masked-max Gram. Block = 4 waves x 64 rows = 256 rows;
// LDS-staged double-buffered 16-col B tiles shared by all 4 waves.
// Grid 16 x 48 = 768 blocks = 3 blocks/CU = 12 waves/CU.
__global__ __launch_bounds__(256) void gram_max_kernel(
        const unsigned short* __restrict__ F,
        const int* __restrict__ labels,
        float* __restrict__ partials) {
    __shared__ unsigned char lds[2][16 * PITCH];
    __shared__ int slab[COLS_PER_CHUNK];         // column labels for this chunk
    int tid = threadIdx.x;
    int wid = tid >> 6, lane = tid & 63;
    int l15 = lane & 15, quad = lane >> 4;
    int rowBase = blockIdx.x * 256 + wid * 64;   // gridDim.x = 16
    int chunk = blockIdx.y;                      // gridDim.y = NCHUNK
    int col0 = chunk * COLS_PER_CHUNK;
    int part = col0 >> 12;                       // block-uniform: 0=aa, 1=p0, 2=p1
    const unsigned char* Fb = (const unsigned char*)F;

    // Stage this chunk's 256 column labels into LDS (labels repeat mod NB).
    slab[tid] = labels[(col0 & (NB - 1)) + tid];

    // Staging map (conflict-free, R3-style): 16 threads per column, each thread
    // two 16B segments at sseg*16 and sseg*16+256. Lanes 0-7 hit banks
    // {0,4,...,28} -> no LDS write conflicts; global side: lanes 0-15 read
    // 256B contiguous.
    int scol = tid >> 4, sseg = tid & 15;

    // Preload A fragments: af[s][kk] covers rows rowBase+s*16.., K = kk*32.
    bf16x8 af[4][8];
    #pragma unroll
    for (int s = 0; s < 4; ++s) {
        const unsigned char* ar = Fb + (size_t)(rowBase + s * 16 + l15) * 512 + quad * 16;
        #pragma unroll
        for (int kk = 0; kk < 8; ++kk)
            af[s][kk] = *(const bf16x8*)(ar + kk * 64);
    }
    // Row labels, byte-packed (labels < 200 fit a byte): rlp[s] holds the 4
    // C rows (quad*4+r) of set s.
    unsigned rlp[4];
    #pragma unroll
    for (int s = 0; s < 4; ++s) {
        const int* lb = labels + rowBase + s * 16 + quad * 4;
        rlp[s] = (unsigned)lb[0] | ((unsigned)lb[1] << 8)
               | ((unsigned)lb[2] << 16) | ((unsigned)lb[3] << 24);
    }

    float vmax[4][4];
    #pragma unroll
    for (int s = 0; s < 4; ++s)
        #pragma unroll
        for (int r = 0; r < 4; ++r) vmax[s][r] = NEG_INIT;

    float4 r0, r1;  // prefetch registers (one 16-col tile / block)
    auto gload = [&](int ct) {
        const unsigned char* g = Fb + (size_t)(col0 + ct * 16 + scol) * 512 + sseg * 16;
        r0 = *(const float4*)g;
        r1 = *(const float4*)(g + 256);
    };
    auto swrite = [&](int buf) {
        unsigned char* p = &lds[buf][scol * PITCH + sseg * 16];
        *(float4*)p = r0;
        *(float4*)(p + 256) = r1;
    };

    gload(0); swrite(0);
    gload(1);
    __syncthreads();

    for (int ct = 0; ct < TILES; ++ct) {
        int buf = ct & 1;
        bf16x8 bfr[8];
        #pragma unroll
        for (int kk = 0; kk < 8; ++kk)
            bfr[kk] = *(const bf16x8*)&lds[buf][l15 * PITCH + quad * 16 + kk * 64];

        if (ct + 1 < TILES) swrite(buf ^ 1);   // stage next tile (regs already loaded)
        if (ct + 2 < TILES) gload(ct + 2);     // prefetch tile after next

        int lc = slab[ct * 16 + l15];          // column label (broadcast within quad)
        unsigned lcq = (unsigned)lc * 0x01010101u;

        // 4 independent MFMA chains (one per 16-row set), depth 8
        f32x4 acc[4];
        #pragma unroll
        for (int s = 0; s < 4; ++s) acc[s] = (f32x4){0.f, 0.f, 0.f, 0.f};
        #pragma unroll
        for (int kk = 0; kk < 8; ++kk)
            #pragma unroll
            for (int s = 0; s < 4; ++s)
                acc[s] = __builtin_amdgcn_mfma_f32_16x16x32_bf16(af[s][kk], bfr[kk], acc[s], 0, 0, 0);

        #pragma unroll
        for (int s = 0; s < 4; ++s) {
            unsigned x = rlp[s] ^ lcq;         // byte r == 0 iff labels equal
            #pragma unroll
            for (int r = 0; r < 4; ++r) {
                bool neq = ((x >> (8 * r)) & 0xffu) != 0u;
                vmax[s][r] = fmaxf(vmax[s][r], neq ? acc[s][r] : NEG_INIT);
            }
        }
        __syncthreads();
    }

    // Reduce max across the 16 column-lanes (same quad = same rows)
    #pragma unroll
    for (int m = 1; m < 16; m <<= 1)
        #pragma unroll
        for (int s = 0; s < 4; ++s)
            #pragma unroll
            for (int r = 0; r < 4; ++r)
                vmax[s][r] = fmaxf(vmax[s][r], __shfl_xor(vmax[s][r], m, 64));

    if (l15 == 0) {
        #pragma unroll
        for (int s = 0; s < 4; ++s)
            #pragma unroll
            for (int r = 0; r < 4; ++r) {
                int row = rowBase + s * 16 + quad * 4 + r;
                partials[(size_t)part * NB * 16 + (size_t)row * 16 + (chunk & 15)] = vmax[s][r];
            }
    }
}

// Kernel 3: combine per-part chunk partials -> neg distances -> hinge -> mean.
__global__ void finalize_kernel(const float* __restrict__ partials,
                                const float* __restrict__ posArr,
                                float* __restrict__ out) {
    int row = blockIdx.x * 256 + threadIdx.x;    // grid = 16 -> 4096 rows
    const float* pa = partials + (size_t)row * 16;
    const float* pb = pa + (size_t)NB * 16;
    const float* pc = pb + (size_t)NB * 16;
    float ma = NEG_INIT, m0 = NEG_INIT, m1 = NEG_INIT;
    #pragma unroll
    for (int j = 0; j < 16; ++j) {
        ma = fmaxf(ma, pa[j]);
        m0 = fmaxf(m0, pb[j]);
        m1 = fmaxf(m1, pc[j]);
    }
    float n0 = sqrtf(fmaxf(2.0f - 2.0f * fmaxf(ma, m0), 1e-12f));
    float n1 = sqrtf(fmaxf(2.0f - 2.0f * fmaxf(ma, m1), 1e-12f));
    float l = fmaxf(posArr[row * 2 + 0] - n0 + 1.0f, 0.0f)
            + fmaxf(posArr[row * 2 + 1] - n1 + 1.0f, 0.0f);
    int lane = threadIdx.x & 63, wid = threadIdx.x >> 6;
    #pragma unroll
    for (int m = 1; m < 64; m <<= 1) l += __shfl_xor(l, m, 64);
    __shared__ float wsum[4];
    if (lane == 0) wsum[wid] = l;
    __syncthreads();
    if (threadIdx.x == 0) {
        float s = wsum[0] + wsum[1] + wsum[2] + wsum[3];
        atomicAdd(out, s * (1.0f / (NB * NP)));
    }
}

extern "C" void kernel_launch(void* const* d_in, const int* in_sizes, int n_in,
                              void* d_out, int out_size, void* d_ws, size_t ws_size,
                              hipStream_t stream) {
    const float* anchor   = (const float*)d_in[0];
    const float* positive = (const float*)d_in[1];
    const int*   labels   = (const int*)d_in[2];
    float* out = (float*)d_out;

    unsigned short* F = (unsigned short*)((char*)d_ws + WS_F_OFF);
    float* posArr     = (float*)((char*)d_ws + WS_POS_OFF);
    float* partials   = (float*)((char*)d_ws + WS_PART_OFF);

    norm_pos_kernel<<<TOT / 4, 256, 0, stream>>>(anchor, positive, F, posArr);
    gram_max_kernel<<<dim3(NB / 256, NCHUNK), 256, 0, stream>>>(F, labels, partials);
    hipMemsetAsync(d_out, 0, sizeof(float), stream);
    finalize_kernel<<<NB / 256, 256, 0, stream>>>(partials, posArr, out);
}

// Round 6
// 104.038 us; speedup vs baseline: 1.2445x; 1.0155x over previous
//
#include <hip/hip_runtime.h>
#include <hip/hip_bf16.h>

// Problem constants
#define NB    4096          // batch
#define ND    256           // dim
#define NP    2             // positives per anchor
#define TOT   (NB * 3)      // 12288 rows: [a | p0 | p1]
#define NCHUNK 48           // 3 parts x 16 chunks; each chunk within one part
#define COLS_PER_CHUNK (TOT / NCHUNK)          // 256
#define TILES (COLS_PER_CHUNK / 16)            // 16
#define PITCH 528                               // 512B row + 16B pad (conflict-free)
#define NEG_INIT (-4.0f)

typedef __bf16 bf16x8 __attribute__((ext_vector_type(8)));
typedef float  f32x4  __attribute__((ext_vector_type(4)));

// ws layout (bytes)
#define WS_F_OFF    0                            // ushort[12288*256] bf16 normalized
#define WS_POS_OFF  (TOT * ND * 2)               // float[4096*2] pos distances
#define WS_PART_OFF (WS_POS_OFF + NB * NP * 4)   // float[3][4096][16] partial maxima

__device__ __forceinline__ unsigned short f2bf(float f) {
    unsigned u = __float_as_uint(f);
    u += 0x7fffu + ((u >> 16) & 1u);   // round-to-nearest-even
    return (unsigned short)(u >> 16);
}

// Kernel 1: normalize rows of [a | p0 | p1] -> bf16 matrix F; p-rows also emit
// the exact fp32 positive distance. One wave per row.
__global__ void norm_pos_kernel(const float* __restrict__ anchor,
                                const float* __restrict__ positive,
                                unsigned short* __restrict__ F,
                                float* __restrict__ posArr) {
    int wid = threadIdx.x >> 6, lane = threadIdx.x & 63;
    int row = blockIdx.x * 4 + wid;              // grid = 3072
    if (row < NB) {
        const float* src = anchor + (size_t)row * ND;
        float4 x = *(const float4*)(src + lane * 4);
        float ss = x.x * x.x + x.y * x.y + x.z * x.z + x.w * x.w;
        #pragma unroll
        for (int m = 1; m < 64; m <<= 1) ss += __shfl_xor(ss, m, 64);
        float inv = 1.0f / fmaxf(sqrtf(ss), 1e-12f);
        ushort4 o;
        o.x = f2bf(x.x * inv); o.y = f2bf(x.y * inv);
        o.z = f2bf(x.z * inv); o.w = f2bf(x.w * inv);
        *(ushort4*)(F + (size_t)row * ND + lane * 4) = o;
    } else {
        int q = row - NB;
        int v = q >> 12;                         // 0 or 1
        int j = q & (NB - 1);
        const float* sp = positive + (size_t)(j * NP + v) * ND;
        const float* sa = anchor + (size_t)j * ND;
        float4 xp = *(const float4*)(sp + lane * 4);
        float4 xa = *(const float4*)(sa + lane * 4);
        float sspv = xp.x * xp.x + xp.y * xp.y + xp.z * xp.z + xp.w * xp.w;
        float ssa  = xa.x * xa.x + xa.y * xa.y + xa.z * xa.z + xa.w * xa.w;
        float dot  = xa.x * xp.x + xa.y * xp.y + xa.z * xp.z + xa.w * xp.w;
        #pragma unroll
        for (int m = 1; m < 64; m <<= 1) {
            sspv += __shfl_xor(sspv, m, 64);
            ssa  += __shfl_xor(ssa, m, 64);
            dot  += __shfl_xor(dot, m, 64);
        }
        float invp = 1.0f / fmaxf(sqrtf(sspv), 1e-12f);
        ushort4 o;
        o.x = f2bf(xp.x * invp); o.y = f2bf(xp.y * invp);
        o.z = f2bf(xp.z * invp); o.w = f2bf(xp.w * invp);
        *(ushort4*)(F + (size_t)row * ND + lane * 4) = o;
        if (lane == 0) {
            float inva = 1.0f / fmaxf(sqrtf(ssa), 1e-12f);
            float dn = dot * inva * invp;
            float sq = 2.0f - 2.0f * dn;
            posArr[j * NP + v] = sqrtf(fmaxf(sq, 1e-12f));
        }
    }
}

// Kernel 2: fused masked-max Gram. Block = 4 waves x 64 rows = 256 rows;
// LDS-staged double-buffered 16-col B tiles shared by all 4 waves.
// 1-D grid of 768 blocks with XCD-aware swizzle: assuming round-robin
// block->XCD dispatch (id % 8), each XCD's 96 resident blocks see only
// 6 B-chunks (0.79 MB) + 16 A row-blocks (2.1 MB) = 2.9 MB < 4 MB L2,
// so the ~200 MB of global re-reads are L2-served instead of L3-served.
__global__ __launch_bounds__(256) void gram_max_kernel(
        const unsigned short* __restrict__ F,
        const int* __restrict__ labels,
        float* __restrict__ partials) {
    __shared__ unsigned char lds[2][16 * PITCH];
    __shared__ int slab[COLS_PER_CHUNK];         // column labels for this chunk
    int tid = threadIdx.x;
    int wid = tid >> 6, lane = tid & 63;
    int l15 = lane & 15, quad = lane >> 4;

    // XCD-aware swizzle (correctness does not depend on the mapping)
    int id = blockIdx.x;                         // 0..767
    int xcd = id & 7, slot = id >> 3;            // slot 0..95
    int chunk = xcd + 8 * (slot % 6);            // 0..47, 6 chunks per XCD
    int rbi   = slot / 6;                        // 0..15 row-block index

    int rowBase = rbi * 256 + wid * 64;
    int col0 = chunk * COLS_PER_CHUNK;
    int part = col0 >> 12;                       // block-uniform: 0=aa, 1=p0, 2=p1
    const unsigned char* Fb = (const unsigned char*)F;

    // Stage this chunk's 256 column labels into LDS (labels repeat mod NB).
    slab[tid] = labels[(col0 & (NB - 1)) + tid];

    // Staging map (conflict-free): 16 threads per column, each thread two 16B
    // segments at sseg*16 and sseg*16+256.
    int scol = tid >> 4, sseg = tid & 15;

    // Preload A fragments: af[s][kk] covers rows rowBase+s*16.., K = kk*32.
    bf16x8 af[4][8];
    #pragma unroll
    for (int s = 0; s < 4; ++s) {
        const unsigned char* ar = Fb + (size_t)(rowBase + s * 16 + l15) * 512 + quad * 16;
        #pragma unroll
        for (int kk = 0; kk < 8; ++kk)
            af[s][kk] = *(const bf16x8*)(ar + kk * 64);
    }
    // Row labels, byte-packed (labels < 200 fit a byte): rlp[s] holds the 4
    // C rows (quad*4+r) of set s.
    unsigned rlp[4];
    #pragma unroll
    for (int s = 0; s < 4; ++s) {
        const int* lb = labels + rowBase + s * 16 + quad * 4;
        rlp[s] = (unsigned)lb[0] | ((unsigned)lb[1] << 8)
               | ((unsigned)lb[2] << 16) | ((unsigned)lb[3] << 24);
    }

    float vmax[4][4];
    #pragma unroll
    for (int s = 0; s < 4; ++s)
        #pragma unroll
        for (int r = 0; r < 4; ++r) vmax[s][r] = NEG_INIT;

    float4 r0, r1;  // prefetch registers (one 16-col tile / block)
    auto gload = [&](int ct) {
        const unsigned char* g = Fb + (size_t)(col0 + ct * 16 + scol) * 512 + sseg * 16;
        r0 = *(const float4*)g;
        r1 = *(const float4*)(g + 256);
    };
    auto swrite = [&](int buf) {
        unsigned char* p = &lds[buf][scol * PITCH + sseg * 16];
        *(float4*)p = r0;
        *(float4*)(p + 256) = r1;
    };

    gload(0); swrite(0);
    gload(1);
    __syncthreads();

    for (int ct = 0; ct < TILES; ++ct) {
        int buf = ct & 1;
        bf16x8 bfr[8];
        #pragma unroll
        for (int kk = 0; kk < 8; ++kk)
            bfr[kk] = *(const bf16x8*)&lds[buf][l15 * PITCH + quad * 16 + kk * 64];

        if (ct + 1 < TILES) swrite(buf ^ 1);   // stage next tile (regs already loaded)
        if (ct + 2 < TILES) gload(ct + 2);     // prefetch tile after next

        int lc = slab[ct * 16 + l15];          // column label
        unsigned lcq = (unsigned)lc * 0x01010101u;

        // 4 independent MFMA chains (one per 16-row set), depth 8
        f32x4 acc[4];
        #pragma unroll
        for (int s = 0; s < 4; ++s) acc[s] = (f32x4){0.f, 0.f, 0.f, 0.f};
        #pragma unroll
        for (int kk = 0; kk < 8; ++kk)
            #pragma unroll
            for (int s = 0; s < 4; ++s)
                acc[s] = __builtin_amdgcn_mfma_f32_16x16x32_bf16(af[s][kk], bfr[kk], acc[s], 0, 0, 0);

        #pragma unroll
        for (int s = 0; s < 4; ++s) {
            unsigned x = rlp[s] ^ lcq;         // byte r == 0 iff labels equal
            #pragma unroll
            for (int r = 0; r < 4; ++r) {
                bool neq = ((x >> (8 * r)) & 0xffu) != 0u;
                vmax[s][r] = fmaxf(vmax[s][r], neq ? acc[s][r] : NEG_INIT);
            }
        }
        __syncthreads();
    }

    // Reduce max across the 16 column-lanes (same quad = same rows)
    #pragma unroll
    for (int m = 1; m < 16; m <<= 1)
        #pragma unroll
        for (int s = 0; s < 4; ++s)
            #pragma unroll
            for (int r = 0; r < 4; ++r)
                vmax[s][r] = fmaxf(vmax[s][r], __shfl_xor(vmax[s][r], m, 64));

    if (l15 == 0) {
        #pragma unroll
        for (int s = 0; s < 4; ++s)
            #pragma unroll
            for (int r = 0; r < 4; ++r) {
                int row = rowBase + s * 16 + quad * 4 + r;
                partials[(size_t)part * NB * 16 + (size_t)row * 16 + (chunk & 15)] = vmax[s][r];
            }
    }
}

// Kernel 3: combine per-part chunk partials -> neg distances -> hinge -> mean.
__global__ void finalize_kernel(const float* __restrict__ partials,
                                const float* __restrict__ posArr,
                                float* __restrict__ out) {
    int row = blockIdx.x * 256 + threadIdx.x;    // grid = 16 -> 4096 rows
    const float* pa = partials + (size_t)row * 16;
    const float* pb = pa + (size_t)NB * 16;
    const float* pc = pb + (size_t)NB * 16;
    float ma = NEG_INIT, m0 = NEG_INIT, m1 = NEG_INIT;
    #pragma unroll
    for (int j = 0; j < 16; ++j) {
        ma = fmaxf(ma, pa[j]);
        m0 = fmaxf(m0, pb[j]);
        m1 = fmaxf(m1, pc[j]);
    }
    float n0 = sqrtf(fmaxf(2.0f - 2.0f * fmaxf(ma, m0), 1e-12f));
    float n1 = sqrtf(fmaxf(2.0f - 2.0f * fmaxf(ma, m1), 1e-12f));
    float l = fmaxf(posArr[row * 2 + 0] - n0 + 1.0f, 0.0f)
            + fmaxf(posArr[row * 2 + 1] - n1 + 1.0f, 0.0f);
    int lane = threadIdx.x & 63, wid = threadIdx.x >> 6;
    #pragma unroll
    for (int m = 1; m < 64; m <<= 1) l += __shfl_xor(l, m, 64);
    __shared__ float wsum[4];
    if (lane == 0) wsum[wid] = l;
    __syncthreads();
    if (threadIdx.x == 0) {
        float s = wsum[0] + wsum[1] + wsum[2] + wsum[3];
        atomicAdd(out, s * (1.0f / (NB * NP)));
    }
}

extern "C" void kernel_launch(void* const* d_in, const int* in_sizes, int n_in,
                              void* d_out, int out_size, void* d_ws, size_t ws_size,
                              hipStream_t stream) {
    const float* anchor   = (const float*)d_in[0];
    const float* positive = (const float*)d_in[1];
    const int*   labels   = (const int*)d_in[2];
    float* out = (float*)d_out;

    unsigned short* F = (unsigned short*)((char*)d_ws + WS_F_OFF);
    float* posArr     = (float*)((char*)d_ws + WS_POS_OFF);
    float* partials   = (float*)((char*)d_ws + WS_PART_OFF);

    norm_pos_kernel<<<TOT / 4, 256, 0, stream>>>(anchor, positive, F, posArr);
    gram_max_kernel<<<(NB / 256) * NCHUNK, 256, 0, stream>>>(F, labels, partials);
    hipMemsetAsync(d_out, 0, sizeof(float), stream);
    finalize_kernel<<<NB / 256, 256, 0, stream>>>(partials, posArr, out);
}